// Round 1
// baseline (401.054 us; speedup 1.0000x reference)
//
#include <hip/hip_runtime.h>
#include <cmath>

// Shapes are fixed by the reference: R=4096, F=256, K=8.
#define R 4096
#define F 256
#define NK 8

typedef _Float16 half8 __attribute__((ext_vector_type(8)));
typedef _Float16 half4v __attribute__((ext_vector_type(4)));
typedef float f32x4 __attribute__((ext_vector_type(4)));

// ---------------------------------------------------------------------------
// ws layout (bytes), total ~4.4 MB:
//   0        : x1h  (4096*256 _Float16)  2 MB
//   2 MB     : x2h  (4096*256 _Float16)  2 MB
//   4 MB     : r1   (4096 f32)  16 KB
//   +16K     : sq1  (4096 f32)
//   +32K     : r2   (4096 f32)
//   +48K     : sq2  (4096 f32)
//   +64K     : S    (8*4096 f32) 128 KB   (softmax denominators)
//   +64K+128K: prm  (32 f32)  [0..7]=w_k  [8..15]=1/(2s^2)  [16..23]=2m  [24..31]=F*m^2
// ---------------------------------------------------------------------------

__global__ __launch_bounds__(256) void prep_kernel(
    const float* __restrict__ x1, const float* __restrict__ x2,
    const float* __restrict__ sigmas, const float* __restrict__ means,
    const float* __restrict__ sigp,
    _Float16* __restrict__ x1h, _Float16* __restrict__ x2h,
    float* __restrict__ r1, float* __restrict__ sq1,
    float* __restrict__ r2, float* __restrict__ sq2,
    float* __restrict__ S, float* __restrict__ prm)
{
    const int tid  = threadIdx.x;
    const int wid  = tid >> 6;
    const int lane = tid & 63;
    const int row  = blockIdx.x * 4 + wid;   // 0..8191: x1 rows then x2 rows

    const float* src; _Float16* dsth; float* rs; float* rq; int r;
    if (row < R) { src = x1; dsth = x1h; rs = r1; rq = sq1; r = row; }
    else         { src = x2; dsth = x2h; rs = r2; rq = sq2; r = row - R; }

    float4 v = ((const float4*)(src + (size_t)r * F))[lane];
    half4v h = { (_Float16)v.x, (_Float16)v.y, (_Float16)v.z, (_Float16)v.w };
    *(half4v*)(dsth + (size_t)r * F + lane * 4) = h;

    float s = v.x + v.y + v.z + v.w;
    float q = v.x * v.x + v.y * v.y + v.z * v.z + v.w * v.w;
    for (int m = 1; m < 64; m <<= 1) {
        s += __shfl_xor(s, m);
        q += __shfl_xor(q, m);
    }
    if (lane == 0) { rs[r] = s; rq[r] = q; }

    // zero softmax-denominator accumulators (ws is poisoned 0xAA each call)
    int g = blockIdx.x * 256 + tid;
    if (g < NK * R) S[g] = 0.f;

    // tiny K=8 parameter prep (runs once; later kernels are stream-ordered after us)
    if (blockIdx.x == 0 && tid == 0) {
        float w[NK], mx = -1e30f;
        for (int k = 0; k < NK; ++k) { float sp = sigp[k]; w[k] = 1.f / (sp * sp); mx = fmaxf(mx, w[k]); }
        float sum = 0.f;
        for (int k = 0; k < NK; ++k) { w[k] = expf(w[k] - mx); sum += w[k]; }
        for (int k = 0; k < NK; ++k) prm[k] = w[k] / sum;
        for (int k = 0; k < NK; ++k) { float sg = sigmas[k]; prm[8 + k] = 1.f / (2.f * sg * sg); }
        for (int k = 0; k < NK; ++k) { float m = means[k]; prm[16 + k] = 2.f * m; prm[24 + k] = (float)F * m * m; }
    }
}

// ---------------------------------------------------------------------------
// 128x128-tile fp16 MFMA GEMM (dot = x1 @ x2^T), fused epilogue.
// PHASE 0: accumulate S[k,i] = sum_j exp(exp(-dist/(2s^2)))   (atomicAdd)
// PHASE 1: out[i,j] = sum_k w_k * exp(kv) / S[k,i]
// Recomputing the GEMM twice is cheaper than storing the 64 MB dot matrix
// (K=256 fp16 GEMM ~ 10-15 us/pass) and keeps ws needs at ~4.4 MB.
// MFMA layouts (guide, m89/m91-verified): A/B frag A[m=lane&15][k=(lane>>4)*8+j];
// D: col=lane&15, row=(lane>>4)*4+reg.
// ---------------------------------------------------------------------------
template <int PHASE>
__global__ __launch_bounds__(256) void gemm_kernel(
    const _Float16* __restrict__ Ah, const _Float16* __restrict__ Bh,
    const float* __restrict__ r1, const float* __restrict__ sq1,
    const float* __restrict__ r2, const float* __restrict__ sq2,
    const float* __restrict__ prm, float* __restrict__ S, float* __restrict__ out)
{
    constexpr int SK = 72;  // 64 + 8-half pad: frag-read row stride 144 B -> 2-way bank alias (free)
    __shared__ _Float16 As[128 * SK];
    __shared__ _Float16 Bs[128 * SK];

    const int tid  = threadIdx.x;
    const int lane = tid & 63;
    const int wid  = tid >> 6;
    const int wm   = wid >> 1, wn = wid & 1;   // 2x2 waves of 64x64
    const int q    = lane >> 4, m16 = lane & 15;
    const int tm   = blockIdx.y, tn = blockIdx.x;

    f32x4 acc[4][4];
    for (int a = 0; a < 4; ++a)
        for (int b = 0; b < 4; ++b)
            acc[a][b] = (f32x4){0.f, 0.f, 0.f, 0.f};

    for (int k0 = 0; k0 < F; k0 += 64) {
        // stage 128x64 halves of each operand; 256 thr x 4 x 16B
        for (int c = 0; c < 4; ++c) {
            int idx = c * 256 + tid;         // 0..1023 chunks of 8 halves
            int row = idx >> 3, c8 = (idx & 7) * 8;
            *(uint4*)&As[row * SK + c8] =
                *(const uint4*)&Ah[(size_t)(tm * 128 + row) * F + k0 + c8];
            *(uint4*)&Bs[row * SK + c8] =
                *(const uint4*)&Bh[(size_t)(tn * 128 + row) * F + k0 + c8];
        }
        __syncthreads();
        for (int s = 0; s < 2; ++s) {
            half8 a[4], b[4];
            for (int mt = 0; mt < 4; ++mt)
                a[mt] = *(const half8*)&As[(wm * 64 + mt * 16 + m16) * SK + s * 32 + q * 8];
            for (int nt = 0; nt < 4; ++nt)
                b[nt] = *(const half8*)&Bs[(wn * 64 + nt * 16 + m16) * SK + s * 32 + q * 8];
            for (int mt = 0; mt < 4; ++mt)
                for (int nt = 0; nt < 4; ++nt)
                    acc[mt][nt] = __builtin_amdgcn_mfma_f32_16x16x32_f16(
                        a[mt], b[nt], acc[mt][nt], 0, 0, 0);
        }
        __syncthreads();
    }

    // ---- epilogue ----
    float wv[8], is2[8], twoM[8], m2F[8];
    for (int k = 0; k < 8; ++k) {
        wv[k] = prm[k]; is2[k] = prm[8 + k]; twoM[k] = prm[16 + k]; m2F[k] = prm[24 + k];
    }
    // dist_k(i,j) = (sq1[i] - 2m*r1[i] + F*m^2) + (sq2[j] + 2m*r2[j]) - 2*dot
    int colg[4]; float colc[8][4];
    for (int nt = 0; nt < 4; ++nt) {
        colg[nt] = tn * 128 + wn * 64 + nt * 16 + m16;
        float c2 = sq2[colg[nt]], cr = r2[colg[nt]];
        for (int k = 0; k < 8; ++k) colc[k][nt] = c2 + twoM[k] * cr;
    }

    for (int mt = 0; mt < 4; ++mt) {
        for (int r = 0; r < 4; ++r) {
            int rowg = tm * 128 + wm * 64 + mt * 16 + q * 4 + r;
            float rq2 = sq1[rowg], rr = r1[rowg];
            if (PHASE == 0) {
                for (int k = 0; k < 8; ++k) {
                    float rowc = rq2 - twoM[k] * rr + m2F[k];
                    float t = 0.f;
                    for (int nt = 0; nt < 4; ++nt) {
                        float dist = rowc + colc[k][nt] - 2.f * acc[mt][nt][r];
                        dist = fminf(fmaxf(dist, 1e-6f), 1e6f);
                        // kv in (0,1] -> softmax without max-subtraction is exact
                        t += expf(expf(-dist * is2[k]));
                    }
                    t += __shfl_xor(t, 1); t += __shfl_xor(t, 2);
                    t += __shfl_xor(t, 4); t += __shfl_xor(t, 8);
                    if (m16 == 0) atomicAdd(&S[k * R + rowg], t);
                }
            } else {
                float sv[8], rowc[8];
                for (int k = 0; k < 8; ++k) {
                    sv[k] = wv[k] / S[k * R + rowg];
                    rowc[k] = rq2 - twoM[k] * rr + m2F[k];
                }
                for (int nt = 0; nt < 4; ++nt) {
                    float d2 = 2.f * acc[mt][nt][r];
                    float o = 0.f;
                    for (int k = 0; k < 8; ++k) {
                        float dist = rowc[k] + colc[k][nt] - d2;
                        dist = fminf(fmaxf(dist, 1e-6f), 1e6f);
                        o += sv[k] * expf(expf(-dist * is2[k]));
                    }
                    out[(size_t)rowg * R + colg[nt]] = o;
                }
            }
        }
    }
}

extern "C" void kernel_launch(void* const* d_in, const int* in_sizes, int n_in,
                              void* d_out, int out_size, void* d_ws, size_t ws_size,
                              hipStream_t stream) {
    (void)in_sizes; (void)n_in; (void)out_size; (void)ws_size;
    const float* x1     = (const float*)d_in[0];
    const float* x2     = (const float*)d_in[1];
    const float* sigmas = (const float*)d_in[2];
    const float* means  = (const float*)d_in[3];
    const float* sigp   = (const float*)d_in[4];
    float* out = (float*)d_out;

    char* ws = (char*)d_ws;
    _Float16* x1h = (_Float16*)ws;
    _Float16* x2h = (_Float16*)(ws + 2097152);
    float* r1  = (float*)(ws + 4194304);
    float* sq1 = (float*)(ws + 4194304 + 16384);
    float* r2  = (float*)(ws + 4194304 + 32768);
    float* sq2 = (float*)(ws + 4194304 + 49152);
    float* S   = (float*)(ws + 4194304 + 65536);
    float* prm = (float*)(ws + 4194304 + 65536 + 131072);

    prep_kernel<<<2048, 256, 0, stream>>>(x1, x2, sigmas, means, sigp,
                                          x1h, x2h, r1, sq1, r2, sq2, S, prm);
    gemm_kernel<0><<<dim3(32, 32), 256, 0, stream>>>(x1h, x2h, r1, sq1, r2, sq2, prm, S, out);
    gemm_kernel<1><<<dim3(32, 32), 256, 0, stream>>>(x1h, x2h, r1, sq1, r2, sq2, prm, S, out);
}

// Round 2
// 199.788 us; speedup vs baseline: 2.0074x; 2.0074x over previous
//
#include <hip/hip_runtime.h>
#include <cmath>

// Shapes fixed by reference: R=4096, F=256, K=8.
#define R 4096
#define F 256
#define NK 8

typedef _Float16 half8 __attribute__((ext_vector_type(8)));
typedef _Float16 half4v __attribute__((ext_vector_type(4)));
typedef float f32x4 __attribute__((ext_vector_type(4)));

#define LOG2E 1.4426950408889634f

// ---------------------------------------------------------------------------
// ws layout (bytes), total ~4.4 MB:
//   0     : x1h (4096*256 f16) 2 MB
//   2 MB  : x2h (4096*256 f16) 2 MB
//   4 MB  : r1, sq1, r2, sq2 (4096 f32 each, 16 KB apart)
//   +64K  : S (8*4096 f32)  -- phase0: softmax denom; finalize: w_k/S
//   +192K : prm (32 f32) [0..7]=w_k [8..15]=1/(2s^2) [16..23]=2m [24..31]=F*m^2
// ---------------------------------------------------------------------------

__global__ __launch_bounds__(256) void prep_kernel(
    const float* __restrict__ x1, const float* __restrict__ x2,
    const float* __restrict__ sigmas, const float* __restrict__ means,
    const float* __restrict__ sigp,
    _Float16* __restrict__ x1h, _Float16* __restrict__ x2h,
    float* __restrict__ r1, float* __restrict__ sq1,
    float* __restrict__ r2, float* __restrict__ sq2,
    float* __restrict__ S, float* __restrict__ prm)
{
    const int tid  = threadIdx.x;
    const int wid  = tid >> 6;
    const int lane = tid & 63;
    const int row  = blockIdx.x * 4 + wid;   // 0..8191: x1 rows then x2 rows

    const float* src; _Float16* dsth; float* rs; float* rq; int r;
    if (row < R) { src = x1; dsth = x1h; rs = r1; rq = sq1; r = row; }
    else         { src = x2; dsth = x2h; rs = r2; rq = sq2; r = row - R; }

    float4 v = ((const float4*)(src + (size_t)r * F))[lane];
    half4v h = { (_Float16)v.x, (_Float16)v.y, (_Float16)v.z, (_Float16)v.w };
    *(half4v*)(dsth + (size_t)r * F + lane * 4) = h;

    float s = v.x + v.y + v.z + v.w;
    float q = v.x * v.x + v.y * v.y + v.z * v.z + v.w * v.w;
    for (int m = 1; m < 64; m <<= 1) {
        s += __shfl_xor(s, m);
        q += __shfl_xor(q, m);
    }
    if (lane == 0) { rs[r] = s; rq[r] = q; }

    // zero softmax-denominator accumulators (ws re-poisoned 0xAA each call)
    int g = blockIdx.x * 256 + tid;
    if (g < NK * R) S[g] = 0.f;

    if (blockIdx.x == 0 && tid == 0) {
        float w[NK], mx = -1e30f;
        for (int k = 0; k < NK; ++k) { float sp = sigp[k]; w[k] = 1.f / (sp * sp); mx = fmaxf(mx, w[k]); }
        float sum = 0.f;
        for (int k = 0; k < NK; ++k) { w[k] = expf(w[k] - mx); sum += w[k]; }
        for (int k = 0; k < NK; ++k) prm[k] = w[k] / sum;
        for (int k = 0; k < NK; ++k) { float sg = sigmas[k]; prm[8 + k] = 1.f / (2.f * sg * sg); }
        for (int k = 0; k < NK; ++k) { float m = means[k]; prm[16 + k] = 2.f * m; prm[24 + k] = (float)F * m * m; }
    }
}

// S[k,i] <- w_k / S[k,i]  (saves per-thread divides in phase 1)
__global__ __launch_bounds__(256) void finalize_kernel(
    float* __restrict__ S, const float* __restrict__ prm)
{
    int g = blockIdx.x * 256 + threadIdx.x;   // 32768 total
    int k = g >> 12;
    S[g] = prm[k] / S[g];
}

// ---------------------------------------------------------------------------
// 128x128-tile fp16 MFMA GEMM (dot = x1 @ x2^T) + fused epilogue.
// PHASE 0: S[k,i] += sum_j exp(exp(-dist/(2s^2)))   (quad-shuffle + atomicAdd)
// PHASE 1: out[i,j] = sum_k (w_k/S[k,i]) * exp(exp(-dist_k))   (S pre-inverted)
// dist_k(i,j) = (sq1[i] - 2m r1[i] + F m^2) + (sq2[j] + 2m r2[j]) - 2 dot(i,j)
// Epilogue is trans-pipe bound: 2 v_exp_f32 per (elem,k); __expf keeps the
// VALU companion work at ~2 ops/exp. launch_bounds(256,2) allows <=256 VGPRs
// so colk[8][4] + acc[4][4] stay in registers (R1 had 304 MB of spill writes).
// ---------------------------------------------------------------------------
template <int PHASE>
__global__ __launch_bounds__(256, 2) void gemm_kernel(
    const _Float16* __restrict__ Ah, const _Float16* __restrict__ Bh,
    const float* __restrict__ r1, const float* __restrict__ sq1,
    const float* __restrict__ r2, const float* __restrict__ sq2,
    const float* __restrict__ prm, float* __restrict__ S, float* __restrict__ out)
{
    constexpr int SK = 72;  // 64 + 8-half pad: 144 B row stride -> 2-way bank alias (free)
    __shared__ _Float16 As[128 * SK];
    __shared__ _Float16 Bs[128 * SK];

    const int tid  = threadIdx.x;
    const int lane = tid & 63;
    const int wid  = tid >> 6;
    const int wm   = wid >> 1, wn = wid & 1;   // 2x2 waves of 64x64
    const int q    = lane >> 4, m16 = lane & 15;
    const int tm   = blockIdx.y, tn = blockIdx.x;

    f32x4 acc[4][4];
#pragma unroll
    for (int a = 0; a < 4; ++a)
#pragma unroll
        for (int b = 0; b < 4; ++b)
            acc[a][b] = (f32x4){0.f, 0.f, 0.f, 0.f};

    for (int k0 = 0; k0 < F; k0 += 64) {
#pragma unroll
        for (int c = 0; c < 4; ++c) {
            int idx = c * 256 + tid;         // 0..1023 chunks of 8 halves
            int row = idx >> 3, c8 = (idx & 7) * 8;
            *(uint4*)&As[row * SK + c8] =
                *(const uint4*)&Ah[(size_t)(tm * 128 + row) * F + k0 + c8];
            *(uint4*)&Bs[row * SK + c8] =
                *(const uint4*)&Bh[(size_t)(tn * 128 + row) * F + k0 + c8];
        }
        __syncthreads();
#pragma unroll
        for (int s = 0; s < 2; ++s) {
            half8 a[4], b[4];
#pragma unroll
            for (int mt = 0; mt < 4; ++mt)
                a[mt] = *(const half8*)&As[(wm * 64 + mt * 16 + m16) * SK + s * 32 + q * 8];
#pragma unroll
            for (int nt = 0; nt < 4; ++nt)
                b[nt] = *(const half8*)&Bs[(wn * 64 + nt * 16 + m16) * SK + s * 32 + q * 8];
#pragma unroll
            for (int mt = 0; mt < 4; ++mt)
#pragma unroll
                for (int nt = 0; nt < 4; ++nt)
                    acc[mt][nt] = __builtin_amdgcn_mfma_f32_16x16x32_f16(
                        a[mt], b[nt], acc[mt][nt], 0, 0, 0);
        }
        __syncthreads();
    }

    // ---- epilogue ----
    // k-indexed params are uniform loads -> SGPRs.
    int colg[4]; float c2[4], cr[4];
#pragma unroll
    for (int nt = 0; nt < 4; ++nt) {
        colg[nt] = tn * 128 + wn * 64 + nt * 16 + m16;
        c2[nt] = sq2[colg[nt]];
        cr[nt] = r2[colg[nt]];
    }
    // colk[k][nt] = sq2[j] + 2m_k r2[j]
    float colk[8][4];
#pragma unroll
    for (int k = 0; k < 8; ++k) {
        float twoM = prm[16 + k];
#pragma unroll
        for (int nt = 0; nt < 4; ++nt) colk[k][nt] = c2[nt] + twoM * cr[nt];
    }

    if (PHASE == 0) {
#pragma unroll
        for (int mt = 0; mt < 4; ++mt) {
#pragma unroll
            for (int r = 0; r < 4; ++r) {
                int rowg = tm * 128 + wm * 64 + mt * 16 + q * 4 + r;
                float rq2 = sq1[rowg], rr = r1[rowg];
#pragma unroll
                for (int k = 0; k < 8; ++k) {
                    float is2  = prm[8 + k];
                    float twoM = prm[16 + k];
                    float m2F  = prm[24 + k];
                    float nis2 = -is2;
                    float rowa = rq2 - twoM * rr + m2F;
                    float t = 0.f;
#pragma unroll
                    for (int nt = 0; nt < 4; ++nt) {
                        float dist = rowa + colk[k][nt] - 2.f * acc[mt][nt][r];
                        dist = fminf(fmaxf(dist, 1e-6f), 1e6f);
                        t += __expf(__expf(dist * nis2));
                    }
                    t += __shfl_xor(t, 1); t += __shfl_xor(t, 2);
                    t += __shfl_xor(t, 4); t += __shfl_xor(t, 8);
                    if (m16 == 0) atomicAdd(&S[k * R + rowg], t);
                }
            }
        }
    } else {
#pragma unroll
        for (int mt = 0; mt < 4; ++mt) {
#pragma unroll
            for (int r = 0; r < 4; ++r) {
                int rowg = tm * 128 + wm * 64 + mt * 16 + q * 4 + r;
                float rq2 = sq1[rowg], rr = r1[rowg];
                float rowa[8], sv[8];
#pragma unroll
                for (int k = 0; k < 8; ++k) {
                    rowa[k] = rq2 - prm[16 + k] * rr + prm[24 + k];
                    sv[k]   = S[k * R + rowg];   // = w_k / denom
                }
#pragma unroll
                for (int nt = 0; nt < 4; ++nt) {
                    float d2 = 2.f * acc[mt][nt][r];
                    float o = 0.f;
#pragma unroll
                    for (int k = 0; k < 8; ++k) {
                        float dist = rowa[k] + colk[k][nt] - d2;
                        dist = fminf(fmaxf(dist, 1e-6f), 1e6f);
                        o += sv[k] * __expf(__expf(dist * -prm[8 + k]));
                    }
                    __builtin_nontemporal_store(o, &out[(size_t)rowg * R + colg[nt]]);
                }
            }
        }
    }
}

extern "C" void kernel_launch(void* const* d_in, const int* in_sizes, int n_in,
                              void* d_out, int out_size, void* d_ws, size_t ws_size,
                              hipStream_t stream) {
    (void)in_sizes; (void)n_in; (void)out_size; (void)ws_size;
    const float* x1     = (const float*)d_in[0];
    const float* x2     = (const float*)d_in[1];
    const float* sigmas = (const float*)d_in[2];
    const float* means  = (const float*)d_in[3];
    const float* sigp   = (const float*)d_in[4];
    float* out = (float*)d_out;

    char* ws = (char*)d_ws;
    _Float16* x1h = (_Float16*)ws;
    _Float16* x2h = (_Float16*)(ws + 2097152);
    float* r1  = (float*)(ws + 4194304);
    float* sq1 = (float*)(ws + 4194304 + 16384);
    float* r2  = (float*)(ws + 4194304 + 32768);
    float* sq2 = (float*)(ws + 4194304 + 49152);
    float* S   = (float*)(ws + 4194304 + 65536);
    float* prm = (float*)(ws + 4194304 + 65536 + 131072);

    prep_kernel<<<2048, 256, 0, stream>>>(x1, x2, sigmas, means, sigp,
                                          x1h, x2h, r1, sq1, r2, sq2, S, prm);
    gemm_kernel<0><<<dim3(32, 32), 256, 0, stream>>>(x1h, x2h, r1, sq1, r2, sq2, prm, S, out);
    finalize_kernel<<<128, 256, 0, stream>>>(S, prm);
    gemm_kernel<1><<<dim3(32, 32), 256, 0, stream>>>(x1h, x2h, r1, sq1, r2, sq2, prm, S, out);
}